// Round 8
// baseline (454.966 us; speedup 1.0000x reference)
//
#include <hip/hip_runtime.h>
#include <math.h>

#define NB 512
#define NN 256
#define NCACHE 64
#define LAP_INF 1e30f
#define ARR_CAP 512

// ws: flag@0, rm1@8K, rj1@8K+512K, rm2@8K+1M, rj2@8K+1.5M, Pt@8K+2M
#define WS_RM1_OFF 8192
#define WS_RJ1_OFF (8192 + (1 << 19))
#define WS_RM2_OFF (8192 + (2 << 19))
#define WS_RJ2_OFF (8192 + 3 * (1 << 19))
#define WS_PT_OFF (8192 + (4 << 19))
#define WS_PT_OFF_MIN 8192

// ---------------------------------------------------------------------------
// pad_mask layout detection: flag = 1 (int32), 2 (float32), 0 (bytes/bool8).
// ---------------------------------------------------------------------------
__global__ __launch_bounds__(1024)
void detect_kernel(const unsigned int* __restrict__ pw, int* __restrict__ flag) {
  __shared__ int notInt, notFloat;
  if (threadIdx.x == 0) { notInt = 0; notFloat = 0; }
  __syncthreads();
  int li = 0, lf = 0;
  for (int t = threadIdx.x; t < 32768; t += 1024) {
    unsigned int w = pw[t];
    if (w > 1u) li = 1;
    if (w != 0u && w != 0x3F800000u) lf = 1;
  }
  if (li) atomicOr(&notInt, 1);
  if (lf) atomicOr(&notFloat, 1);
  __syncthreads();
  if (threadIdx.x == 0) flag[0] = (!notInt) ? 1 : ((!notFloat) ? 2 : 0);
}

// ---------------------------------------------------------------------------
// DPP wave64 u32 min + order/equality-preserving f32<->u32 map.
// ---------------------------------------------------------------------------
template <int CTRL>
__device__ __forceinline__ unsigned dpp_min_step(unsigned x) {
  unsigned y = (unsigned)__builtin_amdgcn_update_dpp((int)x, (int)x, CTRL, 0xF, 0xF, false);
  return y < x ? y : x;
}
__device__ __forceinline__ unsigned wave_min_u32(unsigned x) {
  x = dpp_min_step<0xB1>(x);
  x = dpp_min_step<0x4E>(x);
  x = dpp_min_step<0x141>(x);
  x = dpp_min_step<0x140>(x);
  x = dpp_min_step<0x142>(x);
  x = dpp_min_step<0x143>(x);
  return (unsigned)__builtin_amdgcn_readlane((int)x, 63);
}
__device__ __forceinline__ unsigned f2o(float f) {
  unsigned x = __float_as_uint(f);
  return x ^ ((unsigned)((int)x >> 31) | 0x80000000u);
}
__device__ __forceinline__ float o2f(unsigned m) {
  unsigned x = (m & 0x80000000u) ? (m & 0x7FFFFFFFu) : ~m;
  return __uint_as_float(x);
}
__device__ __forceinline__ int sel4(const int a[4], int s) {
  return (s == 0) ? a[0] : (s == 1) ? a[1] : (s == 2) ? a[2] : a[3];
}
__device__ __forceinline__ void set4(int a[4], int s, int v) {
  if (s == 0) a[0] = v; else if (s == 1) a[1] = v;
  else if (s == 2) a[2] = v; else a[3] = v;
}
__device__ __forceinline__ void setf4(float a[4], int s, float v) {
  if (s == 0) a[0] = v; else if (s == 1) a[1] = v;
  else if (s == 2) a[2] = v; else a[3] = v;
}
__device__ __forceinline__ void subf4(float a[4], int s, float d) {
  if (s == 0) a[0] -= d; else if (s == 1) a[1] -= d;
  else if (s == 2) a[2] -= d; else a[3] -= d;
}

// wave two-smallest of (lm1,lj1) with per-lane runner-up (lm2,lj2)
__device__ __forceinline__ void wave_two_smallest(
    int lane, unsigned lm1, int lj1, unsigned lm2, int lj2,
    unsigned& g1, int& gj1, unsigned& g2, int& gj2) {
  g1 = wave_min_u32(lm1);
  const unsigned long long b1 = __ballot(lm1 == g1);
  const int o1 = __ffsll(b1) - 1;
  gj1 = __builtin_amdgcn_readlane(lj1, o1);
  const unsigned c = (lane == o1) ? lm2 : lm1;
  const int cj = (lane == o1) ? lj2 : lj1;
  g2 = wave_min_u32(c);
  const unsigned long long b2 = __ballot(c == g2);
  const int o2 = __ffsll(b2) - 1;
  gj2 = __builtin_amdgcn_readlane(cj, o2);
}

// per-wave popcount of pad_mask[k] under detected layout (lane covers 4)
__device__ __forceinline__ int wave_nk(const void* pm, int fl, int k, int lane) {
  int cnt4 = 0;
  if (fl == 1) {
    const int* p = ((const int*)pm) + k * NN;
#pragma unroll
    for (int q = 0; q < 4; ++q) cnt4 += (p[lane * 4 + q] != 0);
  } else if (fl == 2) {
    const float* p = ((const float*)pm) + k * NN;
#pragma unroll
    for (int q = 0; q < 4; ++q) cnt4 += (p[lane * 4 + q] != 0.0f);
  } else {
    const unsigned char* p = ((const unsigned char*)pm) + k * NN;
#pragma unroll
    for (int q = 0; q < 4; ++q) cnt4 += (p[lane * 4 + q] != 0);
  }
#pragma unroll
  for (int off = 32; off > 0; off >>= 1) cnt4 += __shfl_down(cnt4, off);
  return __shfl(cnt4, 0);
}

// ---------------------------------------------------------------------------
// Transpose + sanitize rows i < max(n_k, NCACHE) of Pt. n_k inlined.
// ---------------------------------------------------------------------------
__global__ __launch_bounds__(256)
void transpose_kernel(const float* __restrict__ in, float* __restrict__ out,
                      const void* __restrict__ pm, const int* __restrict__ flag) {
  __shared__ float tile[32][33];
  __shared__ int bndS;
  const int k = blockIdx.z;
  // block popcount of mask row k (thread t -> entry t)
  const int fl = flag[0];
  int bit;
  if (fl == 1) bit = (((const int*)pm)[k * NN + threadIdx.x] != 0);
  else if (fl == 2) bit = (((const float*)pm)[k * NN + threadIdx.x] != 0.0f);
  else bit = (((const unsigned char*)pm)[k * NN + threadIdx.x] != 0);
  const unsigned long long bb = __ballot(bit);
  if (threadIdx.x == 0) bndS = 0;
  __syncthreads();
  if ((threadIdx.x & 63) == 0) atomicAdd(&bndS, __popcll(bb));
  __syncthreads();
  int bnd = bndS;
  bnd = bnd > NCACHE ? bnd : NCACHE;
  const int i0 = blockIdx.x * 32;
  if (i0 >= bnd) return;
  const float* A = in + ((size_t)k << 16);
  float* Bp = out + ((size_t)k << 16);
  const int tx = threadIdx.x & 31, ty = threadIdx.x >> 5;
  const int j0 = blockIdx.y * 32;
#pragma unroll
  for (int r = 0; r < 32; r += 8) {
    float x = A[(size_t)(j0 + ty + r) * NN + (i0 + tx)];
    tile[ty + r][tx] = isfinite(x) ? x : 1e6f;
  }
  __syncthreads();
#pragma unroll
  for (int r = 0; r < 32; r += 8) {
    Bp[(size_t)(i0 + ty + r) * NN + (j0 + tx)] = tile[tx][ty + r];
  }
}

// ---------------------------------------------------------------------------
// Per-row two smallest (m1,j1,m2,j2) of Pt, one wave per row. n_k inlined.
// ---------------------------------------------------------------------------
__global__ __launch_bounds__(256)
void rowmin_kernel(const float* __restrict__ Pt, const void* __restrict__ pm,
                   const int* __restrict__ flag,
                   float* __restrict__ rm1, int* __restrict__ rj1,
                   float* __restrict__ rm2, int* __restrict__ rj2) {
  const int k = blockIdx.x;
  const int wid = threadIdx.x >> 6, lane = threadIdx.x & 63;
  const int row = blockIdx.y * 4 + wid;
  const int fl = flag[0];
  const int n_k = wave_nk(pm, fl, k, lane);
  int bnd = n_k > NCACHE ? n_k : NCACHE;
  if (row >= bnd) return;  // wave-uniform exit, no barriers below
  const float4 rv = *(const float4*)(Pt + ((size_t)k << 16) + (size_t)row * NN + lane * 4);
  float w[4] = {rv.x, rv.y, rv.z, rv.w};
  unsigned lm1 = 0xFFFFFFFFu, lm2 = 0xFFFFFFFFu;
  int lj1 = 0, lj2 = 0;
#pragma unroll
  for (int q = 0; q < 4; ++q) {
    const unsigned m = f2o(w[q]);
    const int c = lane * 4 + q;
    if (m < lm1) { lm2 = lm1; lj2 = lj1; lm1 = m; lj1 = c; }
    else if (m < lm2) { lm2 = m; lj2 = c; }
  }
  unsigned g1, g2; int gj1, gj2;
  wave_two_smallest(lane, lm1, lj1, lm2, lj2, g1, gj1, g2, gj2);
  if (lane == 0) {
    rm1[k * NN + row] = o2f(g1);
    rj1[k * NN + row] = gj1;
    rm2[k * NN + row] = o2f(g2);
    rj2[k * NN + row] = gj2;
  }
}

// ---------------------------------------------------------------------------
// One wave64 per batch. Lane L owns cols 4L..4L+3 (v, shortest, pathrow, SC,
// row4col) and rows 4L..4L+3 (u, SR, col4row) in registers.
// Phase 1: greedy row-reduction init (precomputed in mode 2).
// Phase 1.5: JV augmenting row reduction (ARR) on the free-row worklist,
//   with a fast path using precomputed (m1,j1,m2,j2) while v[j1],v[j2] are
//   untouched (v only decreases -> modified cols can't create new minima).
//   Capped; invariants (dual feasibility + tight assigned pairs) hold, so
//   phase 2 completes the unique optimum regardless (validated R2-R6).
// Phase 2: shortest augmenting path for remaining free rows.
// ---------------------------------------------------------------------------
__global__ __launch_bounds__(64)
void lap_kernel(const float* __restrict__ costs, const void* __restrict__ pm,
                const int* __restrict__ flag,
                const float* __restrict__ rm1, const int* __restrict__ rj1,
                const float* __restrict__ rm2, const int* __restrict__ rj2,
                const float* __restrict__ Pt, int* __restrict__ out, int mode) {
  const int k = blockIdx.x;
  const int lane = threadIdx.x;

  __shared__ __align__(16) float rowCache[NCACHE * NN];  // 64 KB
  __shared__ float shortestL[NN];
  __shared__ int qL[768];          // free-row worklist (greedy + ARR appends)
  __shared__ float rm1L[NN]; __shared__ int rj1L[NN];
  __shared__ float rm2L[NN]; __shared__ int rj2L[NN];
  __shared__ unsigned char used[NN];

  const float* PtK = Pt + ((size_t)k << 16);
  const float* costK = costs + ((size_t)k << 16);
  const int fl = flag[0];
  const int n_k = wave_nk(pm, fl, k, lane);

#define LOAD_ROW(ii, cc) do {                                              \
    if ((ii) < NCACHE) {                                                   \
      const float4 rv_ = *(const float4*)(&rowCache[(ii) * NN + lane * 4]);\
      cc[0] = rv_.x; cc[1] = rv_.y; cc[2] = rv_.z; cc[3] = rv_.w;          \
    } else if (mode >= 1) {                                                \
      const float4 rv_ = *(const float4*)(PtK + (size_t)(ii) * NN + lane * 4);\
      cc[0] = rv_.x; cc[1] = rv_.y; cc[2] = rv_.z; cc[3] = rv_.w;          \
    } else {                                                               \
      for (int q_ = 0; q_ < 4; ++q_) {                                     \
        float x_ = costK[(size_t)(lane * 4 + q_) * NN + (ii)];             \
        cc[q_] = isfinite(x_) ? x_ : 1e6f;                                 \
      }                                                                    \
    }                                                                      \
  } while (0)

  // ---- fill LDS row cache + (mode 2) precomputed minima ----
  if (mode >= 1) {
    const float4* s4 = (const float4*)PtK;
    float4* c4 = (float4*)rowCache;
    for (int t = lane; t < NCACHE * (NN / 4); t += 64) c4[t] = s4[t];
  } else {
    for (int e = lane; e < NCACHE * NN; e += 64) {
      const int i = e >> 8, j = e & 255;
      float x = costK[(size_t)j * NN + i];
      rowCache[i * NN + j] = isfinite(x) ? x : 1e6f;
    }
  }
  if (mode == 2) {
    for (int t = lane; t < NN; t += 64) {
      rm1L[t] = rm1[k * NN + t];
      rj1L[t] = rj1[k * NN + t];
      rm2L[t] = rm2[k * NN + t];
      rj2L[t] = rj2[k * NN + t];
    }
  }
  __syncthreads();

  float vv[4] = {0.f, 0.f, 0.f, 0.f};
  float uu[4] = {0.f, 0.f, 0.f, 0.f};
  int r4c[4] = {-1, -1, -1, -1};   // row4col, col-indexed
  int c4r[4] = {-1, -1, -1, -1};   // col4row, row-indexed
  int head = 0, tail = 0;          // wave-uniform worklist bounds

  // ---- phase 1: greedy row-reduction init ----
  if (mode == 2) {
    int ja[4];
#pragma unroll
    for (int q = 0; q < 4; ++q) {
      const int row = lane * 4 + q;
      uu[q] = (row < n_k) ? rm1L[row] : 0.f;
      ja[q] = rj1L[row];
    }
    for (int r = 0; r < n_k; ++r) {
      const int js = __builtin_amdgcn_readlane(sel4(ja, r & 3), r >> 2);
      const int occ = __builtin_amdgcn_readlane(sel4(r4c, js & 3), js >> 2);
      if (occ < 0) {
        if (lane == (js >> 2)) set4(r4c, js & 3, r);
        if (lane == (r >> 2)) set4(c4r, r & 3, js);
      } else {
        if (lane == 0) qL[tail] = r;
        tail++;
      }
    }
  } else {
    // in-lap greedy scan (fallback modes)
    float4 carry = {0.f, 0.f, 0.f, 0.f};
    if (mode >= 1 && NCACHE < n_k)
      carry = *(const float4*)(PtK + (size_t)NCACHE * NN + lane * 4);
    for (int r = 0; r < n_k; ++r) {
      float cc[4];
      if (r < NCACHE) {
        const float4 rv = *(const float4*)(&rowCache[r * NN + lane * 4]);
        cc[0] = rv.x; cc[1] = rv.y; cc[2] = rv.z; cc[3] = rv.w;
      } else if (mode >= 1) {
        cc[0] = carry.x; cc[1] = carry.y; cc[2] = carry.z; cc[3] = carry.w;
      } else {
#pragma unroll
        for (int q = 0; q < 4; ++q) {
          float x = costK[(size_t)(lane * 4 + q) * NN + r];
          cc[q] = isfinite(x) ? x : 1e6f;
        }
      }
      if (mode >= 1 && r + 1 >= NCACHE && r + 1 < n_k)
        carry = *(const float4*)(PtK + (size_t)(r + 1) * NN + lane * 4);
      unsigned lbv = 0xFFFFFFFFu;
      int lbq = 0;
#pragma unroll
      for (int q = 0; q < 4; ++q) {
        const unsigned m = f2o(cc[q]);
        if (m < lbv) { lbv = m; lbq = q; }
      }
      const unsigned gv = wave_min_u32(lbv);
      const unsigned long long cmask = __ballot(lbv == gv);
      const int owner = __ffsll((unsigned long long)cmask) - 1;
      const int js = (owner << 2) + __builtin_amdgcn_readlane(lbq, owner);
      if (lane == (r >> 2)) setf4(uu, r & 3, o2f(gv));
      const int occ = __builtin_amdgcn_readlane(sel4(r4c, js & 3), owner);
      if (occ < 0) {
        if (lane == owner) set4(r4c, js & 3, r);
        if (lane == (r >> 2)) set4(c4r, r & 3, js);
      } else {
        if (lane == 0) qL[tail] = r;
        tail++;
      }
    }
  }

  // ---- phase 1.5: augmenting row reduction (capped worklist) ----
  unsigned vmod = 0;  // per-lane: which of my 4 cols had v modified
  int steps = 0;
  while (head < tail && steps < ARR_CAP) {
    ++steps;
    const int r = qL[head];  // same-address LDS read -> broadcast
    ++head;
    float u1, u2;
    int jj1, jj2;
    bool fast = false;
    if (mode == 2) {
      const int pj1 = rj1L[r], pj2 = rj2L[r];
      const unsigned s1 =
          (unsigned)__builtin_amdgcn_readlane((int)vmod, pj1 >> 2) >> (pj1 & 3);
      const unsigned s2 =
          (unsigned)__builtin_amdgcn_readlane((int)vmod, pj2 >> 2) >> (pj2 & 3);
      if (!((s1 | s2) & 1u)) {
        fast = true;
        u1 = rm1L[r]; u2 = rm2L[r]; jj1 = pj1; jj2 = pj2;
      }
    }
    if (!fast) {
      float cc[4];
      LOAD_ROW(r, cc);
      unsigned lm1 = 0xFFFFFFFFu, lm2 = 0xFFFFFFFFu;
      int lj1 = 0, lj2 = 0;
#pragma unroll
      for (int q = 0; q < 4; ++q) {
        const float w = cc[q] - vv[q];
        const unsigned m = f2o(w);
        const int c = lane * 4 + q;
        if (m < lm1) { lm2 = lm1; lj2 = lj1; lm1 = m; lj1 = c; }
        else if (m < lm2) { lm2 = m; lj2 = c; }
      }
      unsigned g1, g2;
      wave_two_smallest(lane, lm1, lj1, lm2, lj2, g1, jj1, g2, jj2);
      u1 = o2f(g1); u2 = o2f(g2);
    }
    if (u1 < u2) {
      if (lane == (jj1 >> 2)) {
        const int s = jj1 & 3;
        subf4(vv, s, u2 - u1);
        vmod |= (1u << s);
      }
    } else {
      const int occ1 = __builtin_amdgcn_readlane(sel4(r4c, jj1 & 3), jj1 >> 2);
      if (occ1 >= 0) jj1 = jj2;  // tie: take second column
    }
    if (lane == (r >> 2)) setf4(uu, r & 3, u2);
    const int k0 = __builtin_amdgcn_readlane(sel4(r4c, jj1 & 3), jj1 >> 2);
    if (lane == (jj1 >> 2)) set4(r4c, jj1 & 3, r);
    if (lane == (r >> 2)) set4(c4r, r & 3, jj1);
    if (k0 >= 0) {
      if (lane == 0) qL[tail] = k0;  // displaced row re-enters worklist
      tail++;
    }
  }

  // ---- phase 2: shortest augmenting path for remaining free rows ----
  for (int t = head; t < tail; ++t) {
    const int cur = qL[t];
    float sh[4] = {LAP_INF, LAP_INF, LAP_INF, LAP_INF};
    int pr[4] = {-1, -1, -1, -1};
    unsigned scm = 0;
    unsigned srm = 0;
    float minval = 0.f;
    int i = cur, sink = -1;

    while (sink < 0) {
      const int islot = i & 3, iowner = i >> 2;
      if (lane == iowner) srm |= (1u << islot);
      const float su = (islot == 0) ? uu[0] : (islot == 1) ? uu[1]
                     : (islot == 2) ? uu[2] : uu[3];
      const float ui = __int_as_float(
          __builtin_amdgcn_readlane(__float_as_int(su), iowner));

      float cc[4];
      LOAD_ROW(i, cc);

      unsigned lbv = 0xFFFFFFFFu;
      int lbq = 0;
#pragma unroll
      for (int q = 0; q < 4; ++q) {
        float r = minval + cc[q];
        r = r - ui;
        r = r - vv[q];
        const bool sc = (scm >> q) & 1u;
        if (!sc && r < sh[q]) { sh[q] = r; pr[q] = i; }
        const unsigned m = sc ? 0xFFFFFFFFu : f2o(sh[q]);
        if (m < lbv) { lbv = m; lbq = q; }
      }
      const unsigned gv = wave_min_u32(lbv);
      minval = o2f(gv);
      const unsigned long long cmask = __ballot(lbv == gv);
      const int owner = __ffsll((unsigned long long)cmask) - 1;
      const int js = (owner << 2) + __builtin_amdgcn_readlane(lbq, owner);
      if (lane == owner) scm |= (1u << lbq);
      const int nxt = __builtin_amdgcn_readlane(sel4(r4c, js & 3), owner);
      if (nxt < 0) sink = js; else i = nxt;
    }

#pragma unroll
    for (int q = 0; q < 4; ++q) shortestL[lane * 4 + q] = sh[q];
    __syncthreads();

#pragma unroll
    for (int q = 0; q < 4; ++q) {
      if ((srm >> q) & 1u) {
        const int row = lane * 4 + q;
        if (row == cur) uu[q] = uu[q] + minval;
        else uu[q] = uu[q] + (minval - shortestL[c4r[q]]);
      }
      if ((scm >> q) & 1u) vv[q] = vv[q] - (minval - sh[q]);
    }

    int j = sink;
    bool done = false;
    while (!done) {
      const int pi = __builtin_amdgcn_readlane(sel4(pr, j & 3), j >> 2);
      if (lane == (j >> 2)) set4(r4c, j & 3, pi);
      const int jn = __builtin_amdgcn_readlane(sel4(c4r, pi & 3), pi >> 2);
      if (lane == (pi >> 2)) set4(c4r, pi & 3, j);
      done = (pi == cur);
      j = jn;
    }
    __syncthreads();
  }

  // ---- output: valid rows get col4row; padded rows get unused cols asc ----
  for (int t = lane; t < NN; t += 64) used[t] = 0;
  __syncthreads();
#pragma unroll
  for (int q = 0; q < 4; ++q) {
    const int row = lane * 4 + q;
    if (row < n_k) used[c4r[q]] = 1;
  }
  __syncthreads();
  int* outK = out + k * NN;
#pragma unroll
  for (int q = 0; q < 4; ++q) {
    const int row = lane * 4 + q;
    if (row < n_k) outK[row] = c4r[q];
  }
  if (lane == 0) {
    int pos = n_k;
    for (int c = 0; c < NN; ++c)
      if (!used[c]) outK[pos++] = c;
  }
#undef LOAD_ROW
}

extern "C" void kernel_launch(void* const* d_in, const int* in_sizes, int n_in,
                              void* d_out, int out_size, void* d_ws, size_t ws_size,
                              hipStream_t stream) {
  const float* costs = (const float*)d_in[0];
  const void* pm = d_in[1];
  int* out = (int*)d_out;

  int* flag = (int*)d_ws;
  const size_t ptBytes = (size_t)NB * NN * NN * sizeof(float);

  int mode;
  float *rm1, *rm2, *Pt;
  int *rj1, *rj2;
  if (ws_size >= WS_PT_OFF + ptBytes) {
    mode = 2;
    rm1 = (float*)((char*)d_ws + WS_RM1_OFF);
    rj1 = (int*)((char*)d_ws + WS_RJ1_OFF);
    rm2 = (float*)((char*)d_ws + WS_RM2_OFF);
    rj2 = (int*)((char*)d_ws + WS_RJ2_OFF);
    Pt = (float*)((char*)d_ws + WS_PT_OFF);
  } else if (ws_size >= WS_PT_OFF_MIN + ptBytes) {
    mode = 1;
    rm1 = rm2 = (float*)d_ws; rj1 = rj2 = (int*)d_ws;
    Pt = (float*)((char*)d_ws + WS_PT_OFF_MIN);
  } else {
    mode = 0;
    rm1 = rm2 = (float*)d_ws; rj1 = rj2 = (int*)d_ws;
    Pt = (float*)costs;  // unused
  }

  detect_kernel<<<1, 1024, 0, stream>>>((const unsigned int*)pm, flag);
  if (mode >= 1) {
    dim3 g(8, 8, NB);
    transpose_kernel<<<g, 256, 0, stream>>>(costs, Pt, pm, flag);
  }
  if (mode == 2) {
    dim3 g(NB, 64);
    rowmin_kernel<<<g, 256, 0, stream>>>(Pt, pm, flag, rm1, rj1, rm2, rj2);
  }
  lap_kernel<<<NB, 64, 0, stream>>>(costs, pm, flag, rm1, rj1, rm2, rj2, Pt,
                                    out, mode);
}